// Round 29
// baseline (2022.964 us; speedup 1.0000x reference)
//
#include <hip/hip_runtime.h>

// AffinityPropagate (CSPN): B=8, C=32, H=W=256, K=3, prop_time=16.
// R28: WG-slot-cap fix. R22 showed 4096 one-wave workgroups cap at ~8
// waves/CU (occupancy stuck at 20% despite 2x grid) -> per-CU WG-slot
// limit. Pack 4 INDEPENDENT pipeline waves (ty=0..3, each its own
// (h-chunk, channel) task) into one 256-thread WG: 1024 WGs x 4 waves
// = 16 waves/CU. Per-wave code identical to R21/R22 (no LDS/barriers).
// Waves in a block share weight rows (same hblk) -> L1 reuse.
// __launch_bounds__(256,4) pins VGPR<=128 (body needs ~116; no spill).

#define B_ 8
#define C_ 32
#define H_ 256
#define W_ 256
#define CHUNK 16
#define NF 24   // fronts f0..f0+23; needed = CHUNK+6 = 22, rounded to 4

// Planar weights: wts[((b*9)+j)*H*W + h*W + w]
__global__ __launch_bounds__(256)
void prep_weights_kernel(const float* __restrict__ guided,
                         const float* __restrict__ depth,
                         float* __restrict__ wts,
                         int total /* B*H*W */) {
    int idx = blockIdx.x * 256 + threadIdx.x;
    if (idx >= total) return;
    int b  = idx >> 16;        // H*W = 65536
    int hw = idx & 0xFFFF;
    const float* gp = guided + (((size_t)b * 8) << 16) + hw;
    float g[8];
    float m = -3.4e38f;
#pragma unroll
    for (int j = 0; j < 8; j++) { g[j] = gp[(size_t)j << 16]; m = fmaxf(m, g[j]); }
    float s = 0.f;
#pragma unroll
    for (int j = 0; j < 8; j++) { g[j] = expf(g[j] - m); s += g[j]; }
    float inv = 1.0f / s;
    float d = depth[(((size_t)b) << 16) + hw];
    bool fixed = d > 0.f;   // sign(depth) is 0/1 (depth >= 0)
    float* wp = wts + (((size_t)b * 9) << 16) + hw;
#pragma unroll
    for (int j = 0; j < 9; j++) {
        float v;
        if (j == 4) v = fixed ? 1.f : 0.f;            // center
        else        v = fixed ? 0.f : g[j - (j > 4 ? 1 : 0)] * inv;
        wp[(size_t)j << 16] = v;
    }
}

__device__ __forceinline__ float4 zero4() { return make_float4(0.f, 0.f, 0.f, 0.f); }

__device__ __forceinline__ float4 ldxrow(const float* xc, int row, int w0) {
    if (row < 0 || row >= H_) return zero4();
    return *reinterpret_cast<const float4*>(xc + (size_t)row * W_ + w0);
}

// acc[k] += wgt[3i+j][k] * rb[i][k+j]  — same fmaf order as R3..R27 (passed).
__device__ __forceinline__ void stencil4(const float wgt[9][4],
                                         const float rb[3][6],
                                         float acc[4]) {
#pragma unroll
    for (int i = 0; i < 3; ++i)
#pragma unroll
        for (int j = 0; j < 3; ++j)
#pragma unroll
            for (int k = 0; k < 4; ++k)
                acc[k] = fmaf(wgt[i * 3 + j][k], rb[i][k + j], acc[k]);
}

__device__ __forceinline__ void mkrb(float4 v, bool hasL, bool hasR, float rbrow[6]) {
    float lh = __shfl_up(v.w, 1);
    float rh = __shfl_down(v.x, 1);
    rbrow[0] = hasL ? lh : 0.f;
    rbrow[1] = v.x; rbrow[2] = v.y; rbrow[3] = v.z; rbrow[4] = v.w;
    rbrow[5] = hasR ? rh : 0.f;
}

__device__ __forceinline__ void load_wrow(const float* wb, int row, int w0,
                                          size_t plane, float (&w)[9][4]) {
    int qc = min(max(row, 0), H_ - 1);   // clamp; guarded consumers ignore
    const float* wp = wb + (size_t)qc * W_ + w0;
#pragma unroll
    for (int j = 0; j < 9; ++j) {
        float4 v = *reinterpret_cast<const float4*>(wp + j * plane);
        w[j][0] = v.x; w[j][1] = v.y; w[j][2] = v.z; w[j][3] = v.w;
    }
}

// 4 independent pipeline waves per 256-thread WG (ty = wave id).
// Each wave: full 256-wide row (64 lanes x 4 px), own (hblk, channel) task.
__global__ __launch_bounds__(256, 4)
void prop_wave_kernel(const float* __restrict__ xin,
                      const float* __restrict__ wts,
                      float* __restrict__ xout) {
    const int tx = threadIdx.x;            // 0..63
    const int ty = threadIdx.y;            // 0..3 (independent wave)
    const int h0 = blockIdx.x * CHUNK;
    const int c  = blockIdx.y * 4 + ty;    // 4 channels per block
    const int b  = blockIdx.z;
    const int w0 = tx * 4;
    const size_t plane = (size_t)H_ * W_;
    const bool hasL = (tx > 0), hasR = (tx < 63);
    const int f0 = h0 - 3;

    const float* xc = xin + ((size_t)b * C_ + c) * plane;
    const float* wb = wts + (size_t)b * 9 * plane;
    float*       oc = xout + ((size_t)b * C_ + c) * plane;

    // x window: rows f-1, f, f+1
    float4 xm = ldxrow(xc, f0 - 1, w0);
    float4 xq = ldxrow(xc, f0,     w0);
    float4 xp = ldxrow(xc, f0 + 1, w0);
    // carried 2-row windows per stage (zero-init feeds only guarded rows)
    float4 s1a = zero4(), s1b = zero4();   // s1[f-2], s1[f-1]
    float4 s2a = zero4(), s2b = zero4();   // s2[f-3], s2[f-2]
    float4 s3a = zero4(), s3b = zero4();   // s3[f-4], s3[f-3]
    // 4 rotating weight-row buffers: rows f, f-1, f-2, f-3
    float wg0[9][4], wg1[9][4], wg2[9][4], wg3[9][4];
    load_wrow(wb, f0,     w0, plane, wg0);
    load_wrow(wb, f0 - 1, w0, plane, wg1);
    load_wrow(wb, f0 - 2, w0, plane, wg2);
    load_wrow(wb, f0 - 3, w0, plane, wg3);

    auto front = [&](int f, const float (&w1)[9][4], const float (&w2)[9][4],
                     const float (&w3)[9][4], float (&w4)[9][4]) {
        // s1[f]
        float4 n1 = zero4();
        if (f >= 0 && f < H_) {
            float rb[3][6];
            mkrb(xm, hasL, hasR, rb[0]);
            mkrb(xq, hasL, hasR, rb[1]);
            mkrb(xp, hasL, hasR, rb[2]);
            float acc[4] = {0.f, 0.f, 0.f, 0.f};
            stencil4(w1, rb, acc);
            n1 = make_float4(acc[0], acc[1], acc[2], acc[3]);
        }
        // s2[f-1]
        float4 n2 = zero4();
        if (f - 1 >= 0 && f - 1 < H_) {
            float rb[3][6];
            mkrb(s1a, hasL, hasR, rb[0]);
            mkrb(s1b, hasL, hasR, rb[1]);
            mkrb(n1,  hasL, hasR, rb[2]);
            float acc[4] = {0.f, 0.f, 0.f, 0.f};
            stencil4(w2, rb, acc);
            n2 = make_float4(acc[0], acc[1], acc[2], acc[3]);
        }
        // s3[f-2]
        float4 n3 = zero4();
        if (f - 2 >= 0 && f - 2 < H_) {
            float rb[3][6];
            mkrb(s2a, hasL, hasR, rb[0]);
            mkrb(s2b, hasL, hasR, rb[1]);
            mkrb(n2,  hasL, hasR, rb[2]);
            float acc[4] = {0.f, 0.f, 0.f, 0.f};
            stencil4(w3, rb, acc);
            n3 = make_float4(acc[0], acc[1], acc[2], acc[3]);
        }
        // s4[f-3] -> store (consumes w4, freeing it for the reload below)
        const int q = f - 3;
        if (q >= h0 && q < h0 + CHUNK) {
            float rb[3][6];
            mkrb(s3a, hasL, hasR, rb[0]);
            mkrb(s3b, hasL, hasR, rb[1]);
            mkrb(n3,  hasL, hasR, rb[2]);
            float acc[4] = {0.f, 0.f, 0.f, 0.f};
            stencil4(w4, rb, acc);
            *reinterpret_cast<float4*>(oc + (size_t)q * W_ + w0) =
                make_float4(acc[0], acc[1], acc[2], acc[3]);
        }
        // reload w4 with row f+1 (next front's s1 weights); prefetch x[f+2]
        load_wrow(wb, f + 1, w0, plane, w4);
        float4 xn = ldxrow(xc, f + 2, w0);
        // rotate data windows
        xm = xq; xq = xp; xp = xn;
        s1a = s1b; s1b = n1;
        s2a = s2b; s2b = n2;
        s3a = s3b; s3b = n3;
    };

    // 4-unroll rotates weight buffers by NAME (no runtime indexing).
    for (int u = 0; u < NF; u += 4) {
        front(f0 + u + 0, wg0, wg1, wg2, wg3);   // loads f0+u+1 -> wg3
        front(f0 + u + 1, wg3, wg0, wg1, wg2);   // loads f0+u+2 -> wg2
        front(f0 + u + 2, wg2, wg3, wg0, wg1);   // loads f0+u+3 -> wg1
        front(f0 + u + 3, wg1, wg2, wg3, wg0);   // loads f0+u+4 -> wg0
    }
}

extern "C" void kernel_launch(void* const* d_in, const int* in_sizes, int n_in,
                              void* d_out, int out_size, void* d_ws, size_t ws_size,
                              hipStream_t stream) {
    const float* x      = (const float*)d_in[0];
    const float* guided = (const float*)d_in[1];
    const float* depth  = (const float*)d_in[2];
    // d_in[3] = prop_time; fixed to 16 by setup_inputs.
    const int DISPATCHES = 4;    // 16 steps, 4 per dispatch

    float* xbuf = (float*)d_ws;                                   // 64 MB
    float* wts  = (float*)((char*)d_ws +
                           (size_t)B_ * C_ * H_ * W_ * sizeof(float)); // 18.9 MB
    float* out  = (float*)d_out;

    int total = B_ * H_ * W_;
    hipLaunchKernelGGL(prep_weights_kernel, dim3((total + 255) / 256), dim3(256),
                       0, stream, guided, depth, wts, total);

    // 16 hblk x 8 cgroup x 8 b = 1024 WGs x 4 waves = 4096 wave-tasks
    dim3 grid(H_ / CHUNK, C_ / 4, B_), block(64, 4, 1);
    const float* src = x;
    for (int t = 0; t < DISPATCHES; ++t) {
        float* dst = (t == DISPATCHES - 1) ? out : ((t % 2 == 0) ? xbuf : out);
        hipLaunchKernelGGL(prop_wave_kernel, grid, block, 0, stream,
                           src, wts, dst);
        src = dst;
    }
}

// Round 30
// 237.602 us; speedup vs baseline: 8.5141x; 8.5141x over previous
//
#include <hip/hip_runtime.h>

// AffinityPropagate (CSPN): B=8, C=32, H=W=256, K=3, prop_time=16.
// R29: R28 (4 independent pipeline waves per 256-thread WG — WG-slot-cap
// fix, occupancy 20->45% CONFIRMED) minus the register squeeze: R28's
// __launch_bounds__(256,4) pinned VGPR=64 -> 1.18GB spill traffic.
// No min-waves bound: body compiles to ~116 VGPR (R21/R22 measured) ->
// 128-tier -> 4 waves/SIMD -> 4 blocks/CU x 4 waves = 16 waves/CU.

#define B_ 8
#define C_ 32
#define H_ 256
#define W_ 256
#define CHUNK 16
#define NF 24   // fronts f0..f0+23; needed = CHUNK+6 = 22, rounded to 4

// Planar weights: wts[((b*9)+j)*H*W + h*W + w]
__global__ __launch_bounds__(256)
void prep_weights_kernel(const float* __restrict__ guided,
                         const float* __restrict__ depth,
                         float* __restrict__ wts,
                         int total /* B*H*W */) {
    int idx = blockIdx.x * 256 + threadIdx.x;
    if (idx >= total) return;
    int b  = idx >> 16;        // H*W = 65536
    int hw = idx & 0xFFFF;
    const float* gp = guided + (((size_t)b * 8) << 16) + hw;
    float g[8];
    float m = -3.4e38f;
#pragma unroll
    for (int j = 0; j < 8; j++) { g[j] = gp[(size_t)j << 16]; m = fmaxf(m, g[j]); }
    float s = 0.f;
#pragma unroll
    for (int j = 0; j < 8; j++) { g[j] = expf(g[j] - m); s += g[j]; }
    float inv = 1.0f / s;
    float d = depth[(((size_t)b) << 16) + hw];
    bool fixed = d > 0.f;   // sign(depth) is 0/1 (depth >= 0)
    float* wp = wts + (((size_t)b * 9) << 16) + hw;
#pragma unroll
    for (int j = 0; j < 9; j++) {
        float v;
        if (j == 4) v = fixed ? 1.f : 0.f;            // center
        else        v = fixed ? 0.f : g[j - (j > 4 ? 1 : 0)] * inv;
        wp[(size_t)j << 16] = v;
    }
}

__device__ __forceinline__ float4 zero4() { return make_float4(0.f, 0.f, 0.f, 0.f); }

__device__ __forceinline__ float4 ldxrow(const float* xc, int row, int w0) {
    if (row < 0 || row >= H_) return zero4();
    return *reinterpret_cast<const float4*>(xc + (size_t)row * W_ + w0);
}

// acc[k] += wgt[3i+j][k] * rb[i][k+j]  — same fmaf order as R3..R28 (passed).
__device__ __forceinline__ void stencil4(const float wgt[9][4],
                                         const float rb[3][6],
                                         float acc[4]) {
#pragma unroll
    for (int i = 0; i < 3; ++i)
#pragma unroll
        for (int j = 0; j < 3; ++j)
#pragma unroll
            for (int k = 0; k < 4; ++k)
                acc[k] = fmaf(wgt[i * 3 + j][k], rb[i][k + j], acc[k]);
}

__device__ __forceinline__ void mkrb(float4 v, bool hasL, bool hasR, float rbrow[6]) {
    float lh = __shfl_up(v.w, 1);
    float rh = __shfl_down(v.x, 1);
    rbrow[0] = hasL ? lh : 0.f;
    rbrow[1] = v.x; rbrow[2] = v.y; rbrow[3] = v.z; rbrow[4] = v.w;
    rbrow[5] = hasR ? rh : 0.f;
}

__device__ __forceinline__ void load_wrow(const float* wb, int row, int w0,
                                          size_t plane, float (&w)[9][4]) {
    int qc = min(max(row, 0), H_ - 1);   // clamp; guarded consumers ignore
    const float* wp = wb + (size_t)qc * W_ + w0;
#pragma unroll
    for (int j = 0; j < 9; ++j) {
        float4 v = *reinterpret_cast<const float4*>(wp + j * plane);
        w[j][0] = v.x; w[j][1] = v.y; w[j][2] = v.z; w[j][3] = v.w;
    }
}

// 4 independent pipeline waves per 256-thread WG (ty = wave id).
// Each wave: full 256-wide row (64 lanes x 4 px), own (hblk, channel) task.
// No min-waves bound: allocator lands at ~116 VGPR (no spill).
__global__ __launch_bounds__(256)
void prop_wave_kernel(const float* __restrict__ xin,
                      const float* __restrict__ wts,
                      float* __restrict__ xout) {
    const int tx = threadIdx.x;            // 0..63
    const int ty = threadIdx.y;            // 0..3 (independent wave)
    const int h0 = blockIdx.x * CHUNK;
    const int c  = blockIdx.y * 4 + ty;    // 4 channels per block
    const int b  = blockIdx.z;
    const int w0 = tx * 4;
    const size_t plane = (size_t)H_ * W_;
    const bool hasL = (tx > 0), hasR = (tx < 63);
    const int f0 = h0 - 3;

    const float* xc = xin + ((size_t)b * C_ + c) * plane;
    const float* wb = wts + (size_t)b * 9 * plane;
    float*       oc = xout + ((size_t)b * C_ + c) * plane;

    // x window: rows f-1, f, f+1
    float4 xm = ldxrow(xc, f0 - 1, w0);
    float4 xq = ldxrow(xc, f0,     w0);
    float4 xp = ldxrow(xc, f0 + 1, w0);
    // carried 2-row windows per stage (zero-init feeds only guarded rows)
    float4 s1a = zero4(), s1b = zero4();   // s1[f-2], s1[f-1]
    float4 s2a = zero4(), s2b = zero4();   // s2[f-3], s2[f-2]
    float4 s3a = zero4(), s3b = zero4();   // s3[f-4], s3[f-3]
    // 4 rotating weight-row buffers: rows f, f-1, f-2, f-3
    float wg0[9][4], wg1[9][4], wg2[9][4], wg3[9][4];
    load_wrow(wb, f0,     w0, plane, wg0);
    load_wrow(wb, f0 - 1, w0, plane, wg1);
    load_wrow(wb, f0 - 2, w0, plane, wg2);
    load_wrow(wb, f0 - 3, w0, plane, wg3);

    auto front = [&](int f, const float (&w1)[9][4], const float (&w2)[9][4],
                     const float (&w3)[9][4], float (&w4)[9][4]) {
        // s1[f]
        float4 n1 = zero4();
        if (f >= 0 && f < H_) {
            float rb[3][6];
            mkrb(xm, hasL, hasR, rb[0]);
            mkrb(xq, hasL, hasR, rb[1]);
            mkrb(xp, hasL, hasR, rb[2]);
            float acc[4] = {0.f, 0.f, 0.f, 0.f};
            stencil4(w1, rb, acc);
            n1 = make_float4(acc[0], acc[1], acc[2], acc[3]);
        }
        // s2[f-1]
        float4 n2 = zero4();
        if (f - 1 >= 0 && f - 1 < H_) {
            float rb[3][6];
            mkrb(s1a, hasL, hasR, rb[0]);
            mkrb(s1b, hasL, hasR, rb[1]);
            mkrb(n1,  hasL, hasR, rb[2]);
            float acc[4] = {0.f, 0.f, 0.f, 0.f};
            stencil4(w2, rb, acc);
            n2 = make_float4(acc[0], acc[1], acc[2], acc[3]);
        }
        // s3[f-2]
        float4 n3 = zero4();
        if (f - 2 >= 0 && f - 2 < H_) {
            float rb[3][6];
            mkrb(s2a, hasL, hasR, rb[0]);
            mkrb(s2b, hasL, hasR, rb[1]);
            mkrb(n2,  hasL, hasR, rb[2]);
            float acc[4] = {0.f, 0.f, 0.f, 0.f};
            stencil4(w3, rb, acc);
            n3 = make_float4(acc[0], acc[1], acc[2], acc[3]);
        }
        // s4[f-3] -> store (consumes w4, freeing it for the reload below)
        const int q = f - 3;
        if (q >= h0 && q < h0 + CHUNK) {
            float rb[3][6];
            mkrb(s3a, hasL, hasR, rb[0]);
            mkrb(s3b, hasL, hasR, rb[1]);
            mkrb(n3,  hasL, hasR, rb[2]);
            float acc[4] = {0.f, 0.f, 0.f, 0.f};
            stencil4(w4, rb, acc);
            *reinterpret_cast<float4*>(oc + (size_t)q * W_ + w0) =
                make_float4(acc[0], acc[1], acc[2], acc[3]);
        }
        // reload w4 with row f+1 (next front's s1 weights); prefetch x[f+2]
        load_wrow(wb, f + 1, w0, plane, w4);
        float4 xn = ldxrow(xc, f + 2, w0);
        // rotate data windows
        xm = xq; xq = xp; xp = xn;
        s1a = s1b; s1b = n1;
        s2a = s2b; s2b = n2;
        s3a = s3b; s3b = n3;
    };

    // 4-unroll rotates weight buffers by NAME (no runtime indexing).
    for (int u = 0; u < NF; u += 4) {
        front(f0 + u + 0, wg0, wg1, wg2, wg3);   // loads f0+u+1 -> wg3
        front(f0 + u + 1, wg3, wg0, wg1, wg2);   // loads f0+u+2 -> wg2
        front(f0 + u + 2, wg2, wg3, wg0, wg1);   // loads f0+u+3 -> wg1
        front(f0 + u + 3, wg1, wg2, wg3, wg0);   // loads f0+u+4 -> wg0
    }
}

extern "C" void kernel_launch(void* const* d_in, const int* in_sizes, int n_in,
                              void* d_out, int out_size, void* d_ws, size_t ws_size,
                              hipStream_t stream) {
    const float* x      = (const float*)d_in[0];
    const float* guided = (const float*)d_in[1];
    const float* depth  = (const float*)d_in[2];
    // d_in[3] = prop_time; fixed to 16 by setup_inputs.
    const int DISPATCHES = 4;    // 16 steps, 4 per dispatch

    float* xbuf = (float*)d_ws;                                   // 64 MB
    float* wts  = (float*)((char*)d_ws +
                           (size_t)B_ * C_ * H_ * W_ * sizeof(float)); // 18.9 MB
    float* out  = (float*)d_out;

    int total = B_ * H_ * W_;
    hipLaunchKernelGGL(prep_weights_kernel, dim3((total + 255) / 256), dim3(256),
                       0, stream, guided, depth, wts, total);

    // 16 hblk x 8 cgroup x 8 b = 1024 WGs x 4 waves = 4096 wave-tasks
    dim3 grid(H_ / CHUNK, C_ / 4, B_), block(64, 4, 1);
    const float* src = x;
    for (int t = 0; t < DISPATCHES; ++t) {
        float* dst = (t == DISPATCHES - 1) ? out : ((t % 2 == 0) ? xbuf : out);
        hipLaunchKernelGGL(prop_wave_kernel, grid, block, 0, stream,
                           src, wts, dst);
        src = dst;
    }
}

// Round 31
// 199.139 us; speedup vs baseline: 10.1586x; 1.1932x over previous
//
#include <hip/hip_runtime.h>

// AffinityPropagate (CSPN): B=8, C=32, H=W=256, K=3, prop_time=16.
// R30: CHUNK 32 (R21's warm-up-optimal) + 4-wave WG packing (R29's
// placement). The 4 waves (ty=0..3) of a WG process 4 CHANNELS of the same
// (b, hblk): identical weight rows + co-located x support -> L1 dedup of
// the dominant weight-fetch stream. Per-wave code = R21 exactly (no LDS,
// no barriers, 4-step register pipeline). No min-waves bound (R25/R28
// lesson: the allocator squeezes and spills; VGPR floats to ~116).

#define B_ 8
#define C_ 32
#define H_ 256
#define W_ 256
#define CHUNK 32
#define NF 40   // fronts f0..f0+39; needed = CHUNK+6 = 38, rounded to 4

// Planar weights: wts[((b*9)+j)*H*W + h*W + w]
__global__ __launch_bounds__(256)
void prep_weights_kernel(const float* __restrict__ guided,
                         const float* __restrict__ depth,
                         float* __restrict__ wts,
                         int total /* B*H*W */) {
    int idx = blockIdx.x * 256 + threadIdx.x;
    if (idx >= total) return;
    int b  = idx >> 16;        // H*W = 65536
    int hw = idx & 0xFFFF;
    const float* gp = guided + (((size_t)b * 8) << 16) + hw;
    float g[8];
    float m = -3.4e38f;
#pragma unroll
    for (int j = 0; j < 8; j++) { g[j] = gp[(size_t)j << 16]; m = fmaxf(m, g[j]); }
    float s = 0.f;
#pragma unroll
    for (int j = 0; j < 8; j++) { g[j] = expf(g[j] - m); s += g[j]; }
    float inv = 1.0f / s;
    float d = depth[(((size_t)b) << 16) + hw];
    bool fixed = d > 0.f;   // sign(depth) is 0/1 (depth >= 0)
    float* wp = wts + (((size_t)b * 9) << 16) + hw;
#pragma unroll
    for (int j = 0; j < 9; j++) {
        float v;
        if (j == 4) v = fixed ? 1.f : 0.f;            // center
        else        v = fixed ? 0.f : g[j - (j > 4 ? 1 : 0)] * inv;
        wp[(size_t)j << 16] = v;
    }
}

__device__ __forceinline__ float4 zero4() { return make_float4(0.f, 0.f, 0.f, 0.f); }

__device__ __forceinline__ float4 ldxrow(const float* xc, int row, int w0) {
    if (row < 0 || row >= H_) return zero4();
    return *reinterpret_cast<const float4*>(xc + (size_t)row * W_ + w0);
}

// acc[k] += wgt[3i+j][k] * rb[i][k+j]  — same fmaf order as R3..R29 (passed).
__device__ __forceinline__ void stencil4(const float wgt[9][4],
                                         const float rb[3][6],
                                         float acc[4]) {
#pragma unroll
    for (int i = 0; i < 3; ++i)
#pragma unroll
        for (int j = 0; j < 3; ++j)
#pragma unroll
            for (int k = 0; k < 4; ++k)
                acc[k] = fmaf(wgt[i * 3 + j][k], rb[i][k + j], acc[k]);
}

__device__ __forceinline__ void mkrb(float4 v, bool hasL, bool hasR, float rbrow[6]) {
    float lh = __shfl_up(v.w, 1);
    float rh = __shfl_down(v.x, 1);
    rbrow[0] = hasL ? lh : 0.f;
    rbrow[1] = v.x; rbrow[2] = v.y; rbrow[3] = v.z; rbrow[4] = v.w;
    rbrow[5] = hasR ? rh : 0.f;
}

__device__ __forceinline__ void load_wrow(const float* wb, int row, int w0,
                                          size_t plane, float (&w)[9][4]) {
    int qc = min(max(row, 0), H_ - 1);   // clamp; guarded consumers ignore
    const float* wp = wb + (size_t)qc * W_ + w0;
#pragma unroll
    for (int j = 0; j < 9; ++j) {
        float4 v = *reinterpret_cast<const float4*>(wp + j * plane);
        w[j][0] = v.x; w[j][1] = v.y; w[j][2] = v.z; w[j][3] = v.w;
    }
}

// 4 independent pipeline waves per 256-thread WG (ty = channel offset).
// All 4 waves share (b, hblk) -> same weight rows (L1 dedup).
__global__ __launch_bounds__(256)
void prop_wave_kernel(const float* __restrict__ xin,
                      const float* __restrict__ wts,
                      float* __restrict__ xout) {
    const int tx = threadIdx.x;            // 0..63
    const int ty = threadIdx.y;            // 0..3 (independent wave)
    const int h0 = blockIdx.x * CHUNK;
    const int c  = blockIdx.y * 4 + ty;    // 4 channels per block
    const int b  = blockIdx.z;
    const int w0 = tx * 4;
    const size_t plane = (size_t)H_ * W_;
    const bool hasL = (tx > 0), hasR = (tx < 63);
    const int f0 = h0 - 3;

    const float* xc = xin + ((size_t)b * C_ + c) * plane;
    const float* wb = wts + (size_t)b * 9 * plane;
    float*       oc = xout + ((size_t)b * C_ + c) * plane;

    // x window: rows f-1, f, f+1
    float4 xm = ldxrow(xc, f0 - 1, w0);
    float4 xq = ldxrow(xc, f0,     w0);
    float4 xp = ldxrow(xc, f0 + 1, w0);
    // carried 2-row windows per stage (zero-init feeds only guarded rows)
    float4 s1a = zero4(), s1b = zero4();   // s1[f-2], s1[f-1]
    float4 s2a = zero4(), s2b = zero4();   // s2[f-3], s2[f-2]
    float4 s3a = zero4(), s3b = zero4();   // s3[f-4], s3[f-3]
    // 4 rotating weight-row buffers: rows f, f-1, f-2, f-3
    float wg0[9][4], wg1[9][4], wg2[9][4], wg3[9][4];
    load_wrow(wb, f0,     w0, plane, wg0);
    load_wrow(wb, f0 - 1, w0, plane, wg1);
    load_wrow(wb, f0 - 2, w0, plane, wg2);
    load_wrow(wb, f0 - 3, w0, plane, wg3);

    auto front = [&](int f, const float (&w1)[9][4], const float (&w2)[9][4],
                     const float (&w3)[9][4], float (&w4)[9][4]) {
        // s1[f]
        float4 n1 = zero4();
        if (f >= 0 && f < H_) {
            float rb[3][6];
            mkrb(xm, hasL, hasR, rb[0]);
            mkrb(xq, hasL, hasR, rb[1]);
            mkrb(xp, hasL, hasR, rb[2]);
            float acc[4] = {0.f, 0.f, 0.f, 0.f};
            stencil4(w1, rb, acc);
            n1 = make_float4(acc[0], acc[1], acc[2], acc[3]);
        }
        // s2[f-1]
        float4 n2 = zero4();
        if (f - 1 >= 0 && f - 1 < H_) {
            float rb[3][6];
            mkrb(s1a, hasL, hasR, rb[0]);
            mkrb(s1b, hasL, hasR, rb[1]);
            mkrb(n1,  hasL, hasR, rb[2]);
            float acc[4] = {0.f, 0.f, 0.f, 0.f};
            stencil4(w2, rb, acc);
            n2 = make_float4(acc[0], acc[1], acc[2], acc[3]);
        }
        // s3[f-2]
        float4 n3 = zero4();
        if (f - 2 >= 0 && f - 2 < H_) {
            float rb[3][6];
            mkrb(s2a, hasL, hasR, rb[0]);
            mkrb(s2b, hasL, hasR, rb[1]);
            mkrb(n2,  hasL, hasR, rb[2]);
            float acc[4] = {0.f, 0.f, 0.f, 0.f};
            stencil4(w3, rb, acc);
            n3 = make_float4(acc[0], acc[1], acc[2], acc[3]);
        }
        // s4[f-3] -> store (consumes w4, freeing it for the reload below)
        const int q = f - 3;
        if (q >= h0 && q < h0 + CHUNK) {
            float rb[3][6];
            mkrb(s3a, hasL, hasR, rb[0]);
            mkrb(s3b, hasL, hasR, rb[1]);
            mkrb(n3,  hasL, hasR, rb[2]);
            float acc[4] = {0.f, 0.f, 0.f, 0.f};
            stencil4(w4, rb, acc);
            *reinterpret_cast<float4*>(oc + (size_t)q * W_ + w0) =
                make_float4(acc[0], acc[1], acc[2], acc[3]);
        }
        // reload w4 with row f+1 (next front's s1 weights); prefetch x[f+2]
        load_wrow(wb, f + 1, w0, plane, w4);
        float4 xn = ldxrow(xc, f + 2, w0);
        // rotate data windows
        xm = xq; xq = xp; xp = xn;
        s1a = s1b; s1b = n1;
        s2a = s2b; s2b = n2;
        s3a = s3b; s3b = n3;
    };

    // 4-unroll rotates weight buffers by NAME (no runtime indexing).
    for (int u = 0; u < NF; u += 4) {
        front(f0 + u + 0, wg0, wg1, wg2, wg3);   // loads f0+u+1 -> wg3
        front(f0 + u + 1, wg3, wg0, wg1, wg2);   // loads f0+u+2 -> wg2
        front(f0 + u + 2, wg2, wg3, wg0, wg1);   // loads f0+u+3 -> wg1
        front(f0 + u + 3, wg1, wg2, wg3, wg0);   // loads f0+u+4 -> wg0
    }
}

extern "C" void kernel_launch(void* const* d_in, const int* in_sizes, int n_in,
                              void* d_out, int out_size, void* d_ws, size_t ws_size,
                              hipStream_t stream) {
    const float* x      = (const float*)d_in[0];
    const float* guided = (const float*)d_in[1];
    const float* depth  = (const float*)d_in[2];
    // d_in[3] = prop_time; fixed to 16 by setup_inputs.
    const int DISPATCHES = 4;    // 16 steps, 4 per dispatch

    float* xbuf = (float*)d_ws;                                   // 64 MB
    float* wts  = (float*)((char*)d_ws +
                           (size_t)B_ * C_ * H_ * W_ * sizeof(float)); // 18.9 MB
    float* out  = (float*)d_out;

    int total = B_ * H_ * W_;
    hipLaunchKernelGGL(prep_weights_kernel, dim3((total + 255) / 256), dim3(256),
                       0, stream, guided, depth, wts, total);

    // 8 hblk x 8 cgroup x 8 b = 512 WGs x 4 waves = 2048 wave-tasks
    dim3 grid(H_ / CHUNK, C_ / 4, B_), block(64, 4, 1);
    const float* src = x;
    for (int t = 0; t < DISPATCHES; ++t) {
        float* dst = (t == DISPATCHES - 1) ? out : ((t % 2 == 0) ? xbuf : out);
        hipLaunchKernelGGL(prop_wave_kernel, grid, block, 0, stream,
                           src, wts, dst);
        src = dst;
    }
}

// Round 32
// 196.407 us; speedup vs baseline: 10.2998x; 1.0139x over previous
//
#include <hip/hip_runtime.h>

// AffinityPropagate (CSPN): B=8, C=32, H=W=256, K=3, prop_time=16.
// R31: R30 (CHUNK=32, 4 channel-waves/WG sharing weight rows) + ROW-
// CONTIGUOUS weight layout: wts[((b*H+h)*9+j)*W+w]. A row's 9 weight
// vectors = one contiguous 9KB block; consecutive fronts walk adjacent
// blocks -> HW stream prefetch, single weight stream instead of 9 planar
// streams 256KB apart. Loads stay fully coalesced (lanes contiguous in w).

#define B_ 8
#define C_ 32
#define H_ 256
#define W_ 256
#define CHUNK 32
#define NF 40   // fronts f0..f0+39; needed = CHUNK+6 = 38, rounded to 4

// Row-contiguous weights: wts[((b*H + h)*9 + j)*W + w]
__global__ __launch_bounds__(256)
void prep_weights_kernel(const float* __restrict__ guided,
                         const float* __restrict__ depth,
                         float* __restrict__ wts,
                         int total /* B*H*W */) {
    int idx = blockIdx.x * 256 + threadIdx.x;
    if (idx >= total) return;
    int b  = idx >> 16;        // H*W = 65536
    int hw = idx & 0xFFFF;
    int h  = hw >> 8;
    int w  = hw & 255;
    const float* gp = guided + (((size_t)b * 8) << 16) + hw;
    float g[8];
    float m = -3.4e38f;
#pragma unroll
    for (int j = 0; j < 8; j++) { g[j] = gp[(size_t)j << 16]; m = fmaxf(m, g[j]); }
    float s = 0.f;
#pragma unroll
    for (int j = 0; j < 8; j++) { g[j] = expf(g[j] - m); s += g[j]; }
    float inv = 1.0f / s;
    float d = depth[(((size_t)b) << 16) + hw];
    bool fixed = d > 0.f;   // sign(depth) is 0/1 (depth >= 0)
    float* wp = wts + ((size_t)(b * H_ + h) * 9) * W_ + w;
#pragma unroll
    for (int j = 0; j < 9; j++) {
        float v;
        if (j == 4) v = fixed ? 1.f : 0.f;            // center
        else        v = fixed ? 0.f : g[j - (j > 4 ? 1 : 0)] * inv;
        wp[(size_t)j * W_] = v;
    }
}

__device__ __forceinline__ float4 zero4() { return make_float4(0.f, 0.f, 0.f, 0.f); }

__device__ __forceinline__ float4 ldxrow(const float* xc, int row, int w0) {
    if (row < 0 || row >= H_) return zero4();
    return *reinterpret_cast<const float4*>(xc + (size_t)row * W_ + w0);
}

// acc[k] += wgt[3i+j][k] * rb[i][k+j]  — same fmaf order as R3..R30 (passed).
__device__ __forceinline__ void stencil4(const float wgt[9][4],
                                         const float rb[3][6],
                                         float acc[4]) {
#pragma unroll
    for (int i = 0; i < 3; ++i)
#pragma unroll
        for (int j = 0; j < 3; ++j)
#pragma unroll
            for (int k = 0; k < 4; ++k)
                acc[k] = fmaf(wgt[i * 3 + j][k], rb[i][k + j], acc[k]);
}

__device__ __forceinline__ void mkrb(float4 v, bool hasL, bool hasR, float rbrow[6]) {
    float lh = __shfl_up(v.w, 1);
    float rh = __shfl_down(v.x, 1);
    rbrow[0] = hasL ? lh : 0.f;
    rbrow[1] = v.x; rbrow[2] = v.y; rbrow[3] = v.z; rbrow[4] = v.w;
    rbrow[5] = hasR ? rh : 0.f;
}

// Row-contiguous: row r's 9 vectors live in one 9KB block.
__device__ __forceinline__ void load_wrow(const float* wb, int row, int w0,
                                          float (&w)[9][4]) {
    int qc = min(max(row, 0), H_ - 1);   // clamp; guarded consumers ignore
    const float* wp = wb + (size_t)qc * 9 * W_ + w0;
#pragma unroll
    for (int j = 0; j < 9; ++j) {
        float4 v = *reinterpret_cast<const float4*>(wp + j * W_);
        w[j][0] = v.x; w[j][1] = v.y; w[j][2] = v.z; w[j][3] = v.w;
    }
}

// 4 independent pipeline waves per 256-thread WG (ty = channel offset).
// All 4 waves share (b, hblk) -> same weight rows (L1 dedup).
__global__ __launch_bounds__(256)
void prop_wave_kernel(const float* __restrict__ xin,
                      const float* __restrict__ wts,
                      float* __restrict__ xout) {
    const int tx = threadIdx.x;            // 0..63
    const int ty = threadIdx.y;            // 0..3 (independent wave)
    const int h0 = blockIdx.x * CHUNK;
    const int c  = blockIdx.y * 4 + ty;    // 4 channels per block
    const int b  = blockIdx.z;
    const int w0 = tx * 4;
    const size_t plane = (size_t)H_ * W_;
    const bool hasL = (tx > 0), hasR = (tx < 63);
    const int f0 = h0 - 3;

    const float* xc = xin + ((size_t)b * C_ + c) * plane;
    const float* wb = wts + (size_t)b * H_ * 9 * W_;
    float*       oc = xout + ((size_t)b * C_ + c) * plane;

    // x window: rows f-1, f, f+1
    float4 xm = ldxrow(xc, f0 - 1, w0);
    float4 xq = ldxrow(xc, f0,     w0);
    float4 xp = ldxrow(xc, f0 + 1, w0);
    // carried 2-row windows per stage (zero-init feeds only guarded rows)
    float4 s1a = zero4(), s1b = zero4();   // s1[f-2], s1[f-1]
    float4 s2a = zero4(), s2b = zero4();   // s2[f-3], s2[f-2]
    float4 s3a = zero4(), s3b = zero4();   // s3[f-4], s3[f-3]
    // 4 rotating weight-row buffers: rows f, f-1, f-2, f-3
    float wg0[9][4], wg1[9][4], wg2[9][4], wg3[9][4];
    load_wrow(wb, f0,     w0, wg0);
    load_wrow(wb, f0 - 1, w0, wg1);
    load_wrow(wb, f0 - 2, w0, wg2);
    load_wrow(wb, f0 - 3, w0, wg3);

    auto front = [&](int f, const float (&w1)[9][4], const float (&w2)[9][4],
                     const float (&w3)[9][4], float (&w4)[9][4]) {
        // s1[f]
        float4 n1 = zero4();
        if (f >= 0 && f < H_) {
            float rb[3][6];
            mkrb(xm, hasL, hasR, rb[0]);
            mkrb(xq, hasL, hasR, rb[1]);
            mkrb(xp, hasL, hasR, rb[2]);
            float acc[4] = {0.f, 0.f, 0.f, 0.f};
            stencil4(w1, rb, acc);
            n1 = make_float4(acc[0], acc[1], acc[2], acc[3]);
        }
        // s2[f-1]
        float4 n2 = zero4();
        if (f - 1 >= 0 && f - 1 < H_) {
            float rb[3][6];
            mkrb(s1a, hasL, hasR, rb[0]);
            mkrb(s1b, hasL, hasR, rb[1]);
            mkrb(n1,  hasL, hasR, rb[2]);
            float acc[4] = {0.f, 0.f, 0.f, 0.f};
            stencil4(w2, rb, acc);
            n2 = make_float4(acc[0], acc[1], acc[2], acc[3]);
        }
        // s3[f-2]
        float4 n3 = zero4();
        if (f - 2 >= 0 && f - 2 < H_) {
            float rb[3][6];
            mkrb(s2a, hasL, hasR, rb[0]);
            mkrb(s2b, hasL, hasR, rb[1]);
            mkrb(n2,  hasL, hasR, rb[2]);
            float acc[4] = {0.f, 0.f, 0.f, 0.f};
            stencil4(w3, rb, acc);
            n3 = make_float4(acc[0], acc[1], acc[2], acc[3]);
        }
        // s4[f-3] -> store (consumes w4, freeing it for the reload below)
        const int q = f - 3;
        if (q >= h0 && q < h0 + CHUNK) {
            float rb[3][6];
            mkrb(s3a, hasL, hasR, rb[0]);
            mkrb(s3b, hasL, hasR, rb[1]);
            mkrb(n3,  hasL, hasR, rb[2]);
            float acc[4] = {0.f, 0.f, 0.f, 0.f};
            stencil4(w4, rb, acc);
            *reinterpret_cast<float4*>(oc + (size_t)q * W_ + w0) =
                make_float4(acc[0], acc[1], acc[2], acc[3]);
        }
        // reload w4 with row f+1 (next front's s1 weights); prefetch x[f+2]
        load_wrow(wb, f + 1, w0, w4);
        float4 xn = ldxrow(xc, f + 2, w0);
        // rotate data windows
        xm = xq; xq = xp; xp = xn;
        s1a = s1b; s1b = n1;
        s2a = s2b; s2b = n2;
        s3a = s3b; s3b = n3;
    };

    // 4-unroll rotates weight buffers by NAME (no runtime indexing).
    for (int u = 0; u < NF; u += 4) {
        front(f0 + u + 0, wg0, wg1, wg2, wg3);   // loads f0+u+1 -> wg3
        front(f0 + u + 1, wg3, wg0, wg1, wg2);   // loads f0+u+2 -> wg2
        front(f0 + u + 2, wg2, wg3, wg0, wg1);   // loads f0+u+3 -> wg1
        front(f0 + u + 3, wg1, wg2, wg3, wg0);   // loads f0+u+4 -> wg0
    }
}

extern "C" void kernel_launch(void* const* d_in, const int* in_sizes, int n_in,
                              void* d_out, int out_size, void* d_ws, size_t ws_size,
                              hipStream_t stream) {
    const float* x      = (const float*)d_in[0];
    const float* guided = (const float*)d_in[1];
    const float* depth  = (const float*)d_in[2];
    // d_in[3] = prop_time; fixed to 16 by setup_inputs.
    const int DISPATCHES = 4;    // 16 steps, 4 per dispatch

    float* xbuf = (float*)d_ws;                                   // 64 MB
    float* wts  = (float*)((char*)d_ws +
                           (size_t)B_ * C_ * H_ * W_ * sizeof(float)); // 18.9 MB
    float* out  = (float*)d_out;

    int total = B_ * H_ * W_;
    hipLaunchKernelGGL(prep_weights_kernel, dim3((total + 255) / 256), dim3(256),
                       0, stream, guided, depth, wts, total);

    // 8 hblk x 8 cgroup x 8 b = 512 WGs x 4 waves = 2048 wave-tasks
    dim3 grid(H_ / CHUNK, C_ / 4, B_), block(64, 4, 1);
    const float* src = x;
    for (int t = 0; t < DISPATCHES; ++t) {
        float* dst = (t == DISPATCHES - 1) ? out : ((t % 2 == 0) ? xbuf : out);
        hipLaunchKernelGGL(prop_wave_kernel, grid, block, 0, stream,
                           src, wts, dst);
        src = dst;
    }
}

// Round 33
// 189.505 us; speedup vs baseline: 10.6750x; 1.0364x over previous
//
#include <hip/hip_runtime.h>

// AffinityPropagate (CSPN): B=8, C=32, H=W=256, K=3, prop_time=16.
// R32: R31 (CHUNK=32, 4 channel-waves/WG, row-contiguous weights) with the
// dead fronts peeled: NF 40->38 (fronts f0+38/39 store nothing — q outside
// the chunk guard — and their ring writes are dead). 36 unrolled + 2 peel.

#define B_ 8
#define C_ 32
#define H_ 256
#define W_ 256
#define CHUNK 32

// Row-contiguous weights: wts[((b*H + h)*9 + j)*W + w]
__global__ __launch_bounds__(256)
void prep_weights_kernel(const float* __restrict__ guided,
                         const float* __restrict__ depth,
                         float* __restrict__ wts,
                         int total /* B*H*W */) {
    int idx = blockIdx.x * 256 + threadIdx.x;
    if (idx >= total) return;
    int b  = idx >> 16;        // H*W = 65536
    int hw = idx & 0xFFFF;
    int h  = hw >> 8;
    int w  = hw & 255;
    const float* gp = guided + (((size_t)b * 8) << 16) + hw;
    float g[8];
    float m = -3.4e38f;
#pragma unroll
    for (int j = 0; j < 8; j++) { g[j] = gp[(size_t)j << 16]; m = fmaxf(m, g[j]); }
    float s = 0.f;
#pragma unroll
    for (int j = 0; j < 8; j++) { g[j] = expf(g[j] - m); s += g[j]; }
    float inv = 1.0f / s;
    float d = depth[(((size_t)b) << 16) + hw];
    bool fixed = d > 0.f;   // sign(depth) is 0/1 (depth >= 0)
    float* wp = wts + ((size_t)(b * H_ + h) * 9) * W_ + w;
#pragma unroll
    for (int j = 0; j < 9; j++) {
        float v;
        if (j == 4) v = fixed ? 1.f : 0.f;            // center
        else        v = fixed ? 0.f : g[j - (j > 4 ? 1 : 0)] * inv;
        wp[(size_t)j * W_] = v;
    }
}

__device__ __forceinline__ float4 zero4() { return make_float4(0.f, 0.f, 0.f, 0.f); }

__device__ __forceinline__ float4 ldxrow(const float* xc, int row, int w0) {
    if (row < 0 || row >= H_) return zero4();
    return *reinterpret_cast<const float4*>(xc + (size_t)row * W_ + w0);
}

// acc[k] += wgt[3i+j][k] * rb[i][k+j]  — same fmaf order as R3..R31 (passed).
__device__ __forceinline__ void stencil4(const float wgt[9][4],
                                         const float rb[3][6],
                                         float acc[4]) {
#pragma unroll
    for (int i = 0; i < 3; ++i)
#pragma unroll
        for (int j = 0; j < 3; ++j)
#pragma unroll
            for (int k = 0; k < 4; ++k)
                acc[k] = fmaf(wgt[i * 3 + j][k], rb[i][k + j], acc[k]);
}

__device__ __forceinline__ void mkrb(float4 v, bool hasL, bool hasR, float rbrow[6]) {
    float lh = __shfl_up(v.w, 1);
    float rh = __shfl_down(v.x, 1);
    rbrow[0] = hasL ? lh : 0.f;
    rbrow[1] = v.x; rbrow[2] = v.y; rbrow[3] = v.z; rbrow[4] = v.w;
    rbrow[5] = hasR ? rh : 0.f;
}

// Row-contiguous: row r's 9 vectors live in one 9KB block.
__device__ __forceinline__ void load_wrow(const float* wb, int row, int w0,
                                          float (&w)[9][4]) {
    int qc = min(max(row, 0), H_ - 1);   // clamp; guarded consumers ignore
    const float* wp = wb + (size_t)qc * 9 * W_ + w0;
#pragma unroll
    for (int j = 0; j < 9; ++j) {
        float4 v = *reinterpret_cast<const float4*>(wp + j * W_);
        w[j][0] = v.x; w[j][1] = v.y; w[j][2] = v.z; w[j][3] = v.w;
    }
}

// 4 independent pipeline waves per 256-thread WG (ty = channel offset).
// All 4 waves share (b, hblk) -> same weight rows (L1 dedup).
__global__ __launch_bounds__(256)
void prop_wave_kernel(const float* __restrict__ xin,
                      const float* __restrict__ wts,
                      float* __restrict__ xout) {
    const int tx = threadIdx.x;            // 0..63
    const int ty = threadIdx.y;            // 0..3 (independent wave)
    const int h0 = blockIdx.x * CHUNK;
    const int c  = blockIdx.y * 4 + ty;    // 4 channels per block
    const int b  = blockIdx.z;
    const int w0 = tx * 4;
    const size_t plane = (size_t)H_ * W_;
    const bool hasL = (tx > 0), hasR = (tx < 63);
    const int f0 = h0 - 3;

    const float* xc = xin + ((size_t)b * C_ + c) * plane;
    const float* wb = wts + (size_t)b * H_ * 9 * W_;
    float*       oc = xout + ((size_t)b * C_ + c) * plane;

    // x window: rows f-1, f, f+1
    float4 xm = ldxrow(xc, f0 - 1, w0);
    float4 xq = ldxrow(xc, f0,     w0);
    float4 xp = ldxrow(xc, f0 + 1, w0);
    // carried 2-row windows per stage (zero-init feeds only guarded rows)
    float4 s1a = zero4(), s1b = zero4();   // s1[f-2], s1[f-1]
    float4 s2a = zero4(), s2b = zero4();   // s2[f-3], s2[f-2]
    float4 s3a = zero4(), s3b = zero4();   // s3[f-4], s3[f-3]
    // 4 rotating weight-row buffers: rows f, f-1, f-2, f-3
    float wg0[9][4], wg1[9][4], wg2[9][4], wg3[9][4];
    load_wrow(wb, f0,     w0, wg0);
    load_wrow(wb, f0 - 1, w0, wg1);
    load_wrow(wb, f0 - 2, w0, wg2);
    load_wrow(wb, f0 - 3, w0, wg3);

    auto front = [&](int f, const float (&w1)[9][4], const float (&w2)[9][4],
                     const float (&w3)[9][4], float (&w4)[9][4]) {
        // s1[f]
        float4 n1 = zero4();
        if (f >= 0 && f < H_) {
            float rb[3][6];
            mkrb(xm, hasL, hasR, rb[0]);
            mkrb(xq, hasL, hasR, rb[1]);
            mkrb(xp, hasL, hasR, rb[2]);
            float acc[4] = {0.f, 0.f, 0.f, 0.f};
            stencil4(w1, rb, acc);
            n1 = make_float4(acc[0], acc[1], acc[2], acc[3]);
        }
        // s2[f-1]
        float4 n2 = zero4();
        if (f - 1 >= 0 && f - 1 < H_) {
            float rb[3][6];
            mkrb(s1a, hasL, hasR, rb[0]);
            mkrb(s1b, hasL, hasR, rb[1]);
            mkrb(n1,  hasL, hasR, rb[2]);
            float acc[4] = {0.f, 0.f, 0.f, 0.f};
            stencil4(w2, rb, acc);
            n2 = make_float4(acc[0], acc[1], acc[2], acc[3]);
        }
        // s3[f-2]
        float4 n3 = zero4();
        if (f - 2 >= 0 && f - 2 < H_) {
            float rb[3][6];
            mkrb(s2a, hasL, hasR, rb[0]);
            mkrb(s2b, hasL, hasR, rb[1]);
            mkrb(n2,  hasL, hasR, rb[2]);
            float acc[4] = {0.f, 0.f, 0.f, 0.f};
            stencil4(w3, rb, acc);
            n3 = make_float4(acc[0], acc[1], acc[2], acc[3]);
        }
        // s4[f-3] -> store (consumes w4, freeing it for the reload below)
        const int q = f - 3;
        if (q >= h0 && q < h0 + CHUNK) {
            float rb[3][6];
            mkrb(s3a, hasL, hasR, rb[0]);
            mkrb(s3b, hasL, hasR, rb[1]);
            mkrb(n3,  hasL, hasR, rb[2]);
            float acc[4] = {0.f, 0.f, 0.f, 0.f};
            stencil4(w4, rb, acc);
            *reinterpret_cast<float4*>(oc + (size_t)q * W_ + w0) =
                make_float4(acc[0], acc[1], acc[2], acc[3]);
        }
        // reload w4 with row f+1 (next front's s1 weights); prefetch x[f+2]
        load_wrow(wb, f + 1, w0, w4);
        float4 xn = ldxrow(xc, f + 2, w0);
        // rotate data windows
        xm = xq; xq = xp; xp = xn;
        s1a = s1b; s1b = n1;
        s2a = s2b; s2b = n2;
        s3a = s3b; s3b = n3;
    };

    // 36 unrolled fronts (9 rotations of the named weight buffers)...
    for (int u = 0; u < 36; u += 4) {
        front(f0 + u + 0, wg0, wg1, wg2, wg3);   // loads f0+u+1 -> wg3
        front(f0 + u + 1, wg3, wg0, wg1, wg2);   // loads f0+u+2 -> wg2
        front(f0 + u + 2, wg2, wg3, wg0, wg1);   // loads f0+u+3 -> wg1
        front(f0 + u + 3, wg1, wg2, wg3, wg0);   // loads f0+u+4 -> wg0
    }
    // ...+ 2 peeled fronts (36, 37). Fronts 38/39 were dead: their stores
    // target q = h0+35/36 (outside chunk guard), ring writes unconsumed.
    front(f0 + 36, wg0, wg1, wg2, wg3);
    front(f0 + 37, wg3, wg0, wg1, wg2);
}

extern "C" void kernel_launch(void* const* d_in, const int* in_sizes, int n_in,
                              void* d_out, int out_size, void* d_ws, size_t ws_size,
                              hipStream_t stream) {
    const float* x      = (const float*)d_in[0];
    const float* guided = (const float*)d_in[1];
    const float* depth  = (const float*)d_in[2];
    // d_in[3] = prop_time; fixed to 16 by setup_inputs.
    const int DISPATCHES = 4;    // 16 steps, 4 per dispatch

    float* xbuf = (float*)d_ws;                                   // 64 MB
    float* wts  = (float*)((char*)d_ws +
                           (size_t)B_ * C_ * H_ * W_ * sizeof(float)); // 18.9 MB
    float* out  = (float*)d_out;

    int total = B_ * H_ * W_;
    hipLaunchKernelGGL(prep_weights_kernel, dim3((total + 255) / 256), dim3(256),
                       0, stream, guided, depth, wts, total);

    // 8 hblk x 8 cgroup x 8 b = 512 WGs x 4 waves = 2048 wave-tasks
    dim3 grid(H_ / CHUNK, C_ / 4, B_), block(64, 4, 1);
    const float* src = x;
    for (int t = 0; t < DISPATCHES; ++t) {
        float* dst = (t == DISPATCHES - 1) ? out : ((t % 2 == 0) ? xbuf : out);
        hipLaunchKernelGGL(prop_wave_kernel, grid, block, 0, stream,
                           src, wts, dst);
        src = dst;
    }
}